// Round 1
// baseline (1970.272 us; speedup 1.0000x reference)
//
#include <hip/hip_runtime.h>

// ---------------- degree / dinv ----------------
__global__ void deg_init(float* __restrict__ deg, int n) {
    int i = blockIdx.x * blockDim.x + threadIdx.x;
    if (i < n) deg[i] = 1.0f;   // self-loop weight
}

__global__ void deg_accum(const int* __restrict__ col, const float* __restrict__ ew,
                          float* __restrict__ deg, int E) {
    int e = blockIdx.x * blockDim.x + threadIdx.x;
    if (e < E) atomicAdd(&deg[col[e]], ew[e]);
}

__global__ void deg_to_dinv(float* __restrict__ deg, int n) {
    int i = blockIdx.x * blockDim.x + threadIdx.x;
    if (i < n) {
        float d = deg[i];
        deg[i] = d > 0.f ? rsqrtf(d) : 0.f;
    }
}

// ---------------- dense: x[N,16] @ W[16,64] ----------------
__global__ void gemm_in16(const float* __restrict__ x, const float* __restrict__ W,
                          float* __restrict__ out, int n) {
    __shared__ float Ws[16 * 64];
    int t = threadIdx.x;                       // 256 threads
    for (int i = t; i < 16 * 64; i += 256) Ws[i] = W[i];
    __syncthreads();
    int node = blockIdx.x * 4 + (t >> 6);
    int j = t & 63;
    if (node >= n) return;
    const float* xr = x + (size_t)node * 16;
    float acc = 0.f;
#pragma unroll
    for (int k = 0; k < 16; ++k) acc += xr[k] * Ws[k * 64 + j];   // xr[k]: wave-broadcast
    out[(size_t)node * 64 + j] = acc;
}

// ---------------- dense: h[N,64] @ W[64,64] ----------------
__global__ void gemm_hid(const float* __restrict__ h, const float* __restrict__ W,
                         float* __restrict__ out, int n) {
    __shared__ float Ws[64 * 64];
    int t = threadIdx.x;                       // 256 threads
    for (int i = t; i < 64 * 64; i += 256) Ws[i] = W[i];
    __syncthreads();
    int node = blockIdx.x * 4 + (t >> 6);
    int j = t & 63;
    if (node >= n) return;
    float v = h[(size_t)node * 64 + j];        // lane j holds h[n][j], coalesced
    float acc = 0.f;
#pragma unroll
    for (int k = 0; k < 64; ++k)
        acc += __shfl(v, k, 64) * Ws[k * 64 + j];  // LDS: all lanes same k, j=0..63 -> 2-way (free)
    out[(size_t)node * 64 + j] = acc;
}

// ---------------- edge scatter: acc[col] += hpre[row] * norm ----------------
// 16 lanes per edge, 4 channels (float4) per lane.
__global__ void scatter_edges(const int* __restrict__ row, const int* __restrict__ col,
                              const float* __restrict__ ew, const float* __restrict__ dinv,
                              const float* __restrict__ hpre, float* __restrict__ acc, int E) {
    int t = blockIdx.x * blockDim.x + threadIdx.x;
    int e = t >> 4;
    if (e >= E) return;
    int sub = t & 15;
    int r = row[e], c = col[e];                 // broadcast within 16-lane group
    float nrm = dinv[r] * ew[e] * dinv[c];
    const float4 hv = *reinterpret_cast<const float4*>(hpre + (size_t)r * 64 + sub * 4);
    float* dst = acc + (size_t)c * 64 + sub * 4;
    atomicAdd(dst + 0, hv.x * nrm);
    atomicAdd(dst + 1, hv.y * nrm);
    atomicAdd(dst + 2, hv.z * nrm);
    atomicAdd(dst + 3, hv.w * nrm);
}

// ---------------- epilogue: h = [relu](acc + hpre*dinv^2 + b) ----------------
__global__ void epilogue(const float* __restrict__ acc, const float* __restrict__ hpre,
                         const float* __restrict__ dinv, const float* __restrict__ b,
                         float* __restrict__ out, int n, int do_relu) {
    int t = blockIdx.x * blockDim.x + threadIdx.x;
    int node = t >> 6, j = t & 63;
    if (node >= n) return;
    float di = dinv[node];
    size_t idx = (size_t)node * 64 + j;
    float v = acc[idx] + hpre[idx] * di * di + b[j];
    out[idx] = do_relu ? fmaxf(v, 0.f) : v;
}

// ---------------- head: out[n,2] = h[n,:] @ Wl + bl ----------------
__global__ void head(const float* __restrict__ h, const float* __restrict__ Wl,
                     const float* __restrict__ bl, float* __restrict__ out, int n) {
    int wave = (blockIdx.x * blockDim.x + threadIdx.x) >> 6;
    int lane = threadIdx.x & 63;
    if (wave >= n) return;
    float v = h[(size_t)wave * 64 + lane];      // coalesced 256B per wave
    float s0 = v * Wl[lane * 2 + 0];
    float s1 = v * Wl[lane * 2 + 1];
#pragma unroll
    for (int off = 32; off > 0; off >>= 1) {
        s0 += __shfl_down(s0, off, 64);
        s1 += __shfl_down(s1, off, 64);
    }
    if (lane == 0) {
        out[(size_t)wave * 2 + 0] = s0 + bl[0];
        out[(size_t)wave * 2 + 1] = s1 + bl[1];
    }
}

extern "C" void kernel_launch(void* const* d_in, const int* in_sizes, int n_in,
                              void* d_out, int out_size, void* d_ws, size_t ws_size,
                              hipStream_t stream) {
    const float* x  = (const float*)d_in[0];
    const int*   ei = (const int*)d_in[1];
    const float* ew = (const float*)d_in[2];
    const float* W1 = (const float*)d_in[3];
    const float* b1 = (const float*)d_in[4];
    const float* W2 = (const float*)d_in[5];
    const float* b2 = (const float*)d_in[6];
    const float* Wl = (const float*)d_in[7];
    const float* bl = (const float*)d_in[8];
    float* out = (float*)d_out;

    const int N = in_sizes[0] / 16;
    const int E = in_sizes[2];
    const int* row = ei;
    const int* col = ei + E;

    float* ws   = (float*)d_ws;
    float* dinv = ws;                                // N
    float* bufA = ws + N;                            // N*64 (pre-activation)
    float* bufB = bufA + (size_t)N * 64;             // N*64 (accumulator / h)

    // ---- degree / dinv (shared by both layers) ----
    deg_init<<<(N + 255) / 256, 256, 0, stream>>>(dinv, N);
    deg_accum<<<(E + 255) / 256, 256, 0, stream>>>(col, ew, dinv, E);
    deg_to_dinv<<<(N + 255) / 256, 256, 0, stream>>>(dinv, N);

    // ---- layer 1 ----
    gemm_in16<<<(N + 3) / 4, 256, 0, stream>>>(x, W1, bufA, N);
    hipMemsetAsync(bufB, 0, (size_t)N * 64 * sizeof(float), stream);
    scatter_edges<<<((size_t)E * 16 + 255) / 256, 256, 0, stream>>>(row, col, ew, dinv, bufA, bufB, E);
    epilogue<<<((size_t)N * 64 + 255) / 256, 256, 0, stream>>>(bufB, bufA, dinv, b1, bufB, N, 1);

    // ---- layer 2 ----
    gemm_hid<<<(N + 3) / 4, 256, 0, stream>>>(bufB, W2, bufA, N);
    hipMemsetAsync(bufB, 0, (size_t)N * 64 * sizeof(float), stream);
    scatter_edges<<<((size_t)E * 16 + 255) / 256, 256, 0, stream>>>(row, col, ew, dinv, bufA, bufB, E);
    epilogue<<<((size_t)N * 64 + 255) / 256, 256, 0, stream>>>(bufB, bufA, dinv, b2, bufB, N, 1);

    // ---- head ----
    head<<<(N + 3) / 4, 256, 0, stream>>>(bufB, Wl, bl, out, N);
}

// Round 2
// 498.199 us; speedup vs baseline: 3.9548x; 3.9548x over previous
//
#include <hip/hip_runtime.h>

// ---------------- histogram of destination degree (edge counts) ----------------
__global__ void hist_col(const int* __restrict__ col, int* __restrict__ cnt, int E) {
    int e = blockIdx.x * blockDim.x + threadIdx.x;
    if (e < E) atomicAdd(&cnt[col[e]], 1);
}

// ---------------- single-block exclusive scan: cnt[n] -> start[n+1] ----------------
__global__ void scan_offsets(const int* __restrict__ cnt, int* __restrict__ start, int n) {
    __shared__ int sums[1024];
    int t = threadIdx.x;                     // 1024 threads
    int ch = (n + 1023) / 1024;
    int base = t * ch;
    int s = 0;
    for (int i = 0; i < ch; ++i) { int idx = base + i; if (idx < n) s += cnt[idx]; }
    sums[t] = s;
    __syncthreads();
    for (int off = 1; off < 1024; off <<= 1) {   // Hillis-Steele inclusive scan
        int v = (t >= off) ? sums[t - off] : 0;
        __syncthreads();
        sums[t] += v;
        __syncthreads();
    }
    int run = (t == 0) ? 0 : sums[t - 1];        // exclusive prefix of this chunk
    for (int i = 0; i < ch; ++i) {
        int idx = base + i;
        if (idx < n) { int c = cnt[idx]; start[idx] = run; run += c; }
    }
    if (t == 1023) start[n] = run;
}

// ---------------- degree / dinv ----------------
__global__ void deg_init(float* __restrict__ deg, int n) {
    int i = blockIdx.x * blockDim.x + threadIdx.x;
    if (i < n) deg[i] = 1.0f;   // self-loop weight
}

__global__ void deg_accum(const int* __restrict__ col, const float* __restrict__ ew,
                          float* __restrict__ deg, int E) {
    int e = blockIdx.x * blockDim.x + threadIdx.x;
    if (e < E) atomicAdd(&deg[col[e]], ew[e]);
}

__global__ void deg_to_dinv(float* __restrict__ deg, int n) {
    int i = blockIdx.x * blockDim.x + threadIdx.x;
    if (i < n) {
        float d = deg[i];
        deg[i] = d > 0.f ? rsqrtf(d) : 0.f;
    }
}

// ---------------- bin edges into CSR order, precompute norm ----------------
__global__ void bin_edges(const int* __restrict__ row, const int* __restrict__ col,
                          const float* __restrict__ ew, const float* __restrict__ dinv,
                          const int* __restrict__ start, int* __restrict__ cursor,
                          int* __restrict__ srow, float* __restrict__ snrm, int E) {
    int e = blockIdx.x * blockDim.x + threadIdx.x;
    if (e >= E) return;
    int c = col[e], r = row[e];
    int pos = start[c] + atomicAdd(&cursor[c], 1);
    srow[pos] = r;
    snrm[pos] = dinv[r] * ew[e] * dinv[c];
}

// ---------------- dense: x[N,16] @ W[16,64] ----------------
__global__ void gemm_in16(const float* __restrict__ x, const float* __restrict__ W,
                          float* __restrict__ out, int n) {
    __shared__ float Ws[16 * 64];
    int t = threadIdx.x;                       // 256 threads
    for (int i = t; i < 16 * 64; i += 256) Ws[i] = W[i];
    __syncthreads();
    int node = blockIdx.x * 4 + (t >> 6);
    int j = t & 63;
    if (node >= n) return;
    const float* xr = x + (size_t)node * 16;
    float acc = 0.f;
#pragma unroll
    for (int k = 0; k < 16; ++k) acc += xr[k] * Ws[k * 64 + j];
    out[(size_t)node * 64 + j] = acc;
}

// ---------------- dense: h[N,64] @ W[64,64] ----------------
__global__ void gemm_hid(const float* __restrict__ h, const float* __restrict__ W,
                         float* __restrict__ out, int n) {
    __shared__ float Ws[64 * 64];
    int t = threadIdx.x;                       // 256 threads
    for (int i = t; i < 64 * 64; i += 256) Ws[i] = W[i];
    __syncthreads();
    int node = blockIdx.x * 4 + (t >> 6);
    int j = t & 63;
    if (node >= n) return;
    float v = h[(size_t)node * 64 + j];
    float acc = 0.f;
#pragma unroll
    for (int k = 0; k < 64; ++k)
        acc += __shfl(v, k, 64) * Ws[k * 64 + j];
    out[(size_t)node * 64 + j] = acc;
}

// ---------------- gather: one wave per destination node, lane = channel ----------------
// out[c][j] = relu( sum_e hpre[srow[e]][j]*snrm[e] + hpre[c][j]*dinv[c]^2 + b[j] )
__global__ void gather_nodes(const int* __restrict__ start, const int* __restrict__ srow,
                             const float* __restrict__ snrm, const float* __restrict__ hpre,
                             const float* __restrict__ dinv, const float* __restrict__ b,
                             float* __restrict__ out, int n, int do_relu) {
    int wid = (blockIdx.x * blockDim.x + threadIdx.x) >> 6;  // node id
    int lane = threadIdx.x & 63;
    if (wid >= n) return;
    int s = start[wid], e = start[wid + 1];
    float di = dinv[wid];
    float acc = hpre[(size_t)wid * 64 + lane] * (di * di) + b[lane];
    int i = s;
    for (; i + 1 < e; i += 2) {                 // 2-edge ILP: both gathers in flight
        int   r0 = srow[i],     r1 = srow[i + 1];   // wave-uniform -> broadcast load
        float w0 = snrm[i],     w1 = snrm[i + 1];
        float v0 = hpre[(size_t)r0 * 64 + lane];    // coalesced 256B
        float v1 = hpre[(size_t)r1 * 64 + lane];
        acc += v0 * w0;
        acc += v1 * w1;
    }
    if (i < e) {
        int r = srow[i];
        acc += hpre[(size_t)r * 64 + lane] * snrm[i];
    }
    if (do_relu) acc = fmaxf(acc, 0.f);
    out[(size_t)wid * 64 + lane] = acc;
}

// ---------------- head: out[n,2] = h[n,:] @ Wl + bl ----------------
__global__ void head(const float* __restrict__ h, const float* __restrict__ Wl,
                     const float* __restrict__ bl, float* __restrict__ out, int n) {
    int wave = (blockIdx.x * blockDim.x + threadIdx.x) >> 6;
    int lane = threadIdx.x & 63;
    if (wave >= n) return;
    float v = h[(size_t)wave * 64 + lane];
    float s0 = v * Wl[lane * 2 + 0];
    float s1 = v * Wl[lane * 2 + 1];
#pragma unroll
    for (int off = 32; off > 0; off >>= 1) {
        s0 += __shfl_down(s0, off, 64);
        s1 += __shfl_down(s1, off, 64);
    }
    if (lane == 0) {
        out[(size_t)wave * 2 + 0] = s0 + bl[0];
        out[(size_t)wave * 2 + 1] = s1 + bl[1];
    }
}

extern "C" void kernel_launch(void* const* d_in, const int* in_sizes, int n_in,
                              void* d_out, int out_size, void* d_ws, size_t ws_size,
                              hipStream_t stream) {
    const float* x  = (const float*)d_in[0];
    const int*   ei = (const int*)d_in[1];
    const float* ew = (const float*)d_in[2];
    const float* W1 = (const float*)d_in[3];
    const float* b1 = (const float*)d_in[4];
    const float* W2 = (const float*)d_in[5];
    const float* b2 = (const float*)d_in[6];
    const float* Wl = (const float*)d_in[7];
    const float* bl = (const float*)d_in[8];
    float* out = (float*)d_out;

    const int N = in_sizes[0] / 16;
    const int E = in_sizes[2];
    const int* row = ei;
    const int* col = ei + E;

    // workspace layout (floats/ints, 4B each)
    char* p = (char*)d_ws;
    float* dinv   = (float*)p;  p += (size_t)N * 4;
    float* bufA   = (float*)p;  p += (size_t)N * 64 * 4;
    float* bufB   = (float*)p;  p += (size_t)N * 64 * 4;
    int*   startO = (int*)p;    p += (size_t)(N + 1) * 4;
    int*   cursor = (int*)p;    p += (size_t)N * 4;
    int*   srow   = (int*)p;    p += (size_t)E * 4;
    float* snrm   = (float*)p;  p += (size_t)E * 4;

    // ---- build CSR by destination (shared by both layers) ----
    hipMemsetAsync(cursor, 0, (size_t)N * sizeof(int), stream);
    hist_col<<<(E + 255) / 256, 256, 0, stream>>>(col, cursor, E);
    scan_offsets<<<1, 1024, 0, stream>>>(cursor, startO, N);

    deg_init<<<(N + 255) / 256, 256, 0, stream>>>(dinv, N);
    deg_accum<<<(E + 255) / 256, 256, 0, stream>>>(col, ew, dinv, E);
    deg_to_dinv<<<(N + 255) / 256, 256, 0, stream>>>(dinv, N);

    hipMemsetAsync(cursor, 0, (size_t)N * sizeof(int), stream);
    bin_edges<<<(E + 255) / 256, 256, 0, stream>>>(row, col, ew, dinv, startO, cursor, srow, snrm, E);

    // ---- layer 1 ----
    gemm_in16<<<(N + 3) / 4, 256, 0, stream>>>(x, W1, bufA, N);
    gather_nodes<<<(N + 3) / 4, 256, 0, stream>>>(startO, srow, snrm, bufA, dinv, b1, bufB, N, 1);

    // ---- layer 2 ----
    gemm_hid<<<(N + 3) / 4, 256, 0, stream>>>(bufB, W2, bufA, N);
    gather_nodes<<<(N + 3) / 4, 256, 0, stream>>>(startO, srow, snrm, bufA, dinv, b2, bufB, N, 1);

    // ---- head ----
    head<<<(N + 3) / 4, 256, 0, stream>>>(bufB, Wl, bl, out, N);
}

// Round 3
// 341.420 us; speedup vs baseline: 5.7708x; 1.4592x over previous
//
#include <hip/hip_runtime.h>

// ---------------- edge pass 1: histogram (count) + weighted degree ----------------
__global__ void hist_deg(const int* __restrict__ col, const float* __restrict__ ew,
                         int* __restrict__ cnt, float* __restrict__ deg, int E) {
    int e = blockIdx.x * blockDim.x + threadIdx.x;
    if (e < E) {
        int c = col[e];
        atomicAdd(&cnt[c], 1);
        atomicAdd(&deg[c], ew[e]);
    }
}

// ---------------- scan stage 1: per-block (256) exclusive scan ----------------
__global__ void scan1(const int* __restrict__ cnt, int* __restrict__ start,
                      int* __restrict__ bsum, int n) {
    __shared__ int sd[256];
    int t = threadIdx.x;
    int i = blockIdx.x * 256 + t;
    int v = (i < n) ? cnt[i] : 0;
    sd[t] = v;
    __syncthreads();
    for (int off = 1; off < 256; off <<= 1) {   // Hillis-Steele inclusive
        int x = (t >= off) ? sd[t - off] : 0;
        __syncthreads();
        sd[t] += x;
        __syncthreads();
    }
    if (i < n) start[i] = sd[t] - v;            // local exclusive
    if (t == 255) bsum[blockIdx.x] = sd[255];   // block total
}

// ---------------- scan stage 2: single block scans block sums (nb <= 1024) ----------------
__global__ void scan2(const int* __restrict__ bsum, int* __restrict__ boff,
                      int* __restrict__ start, int nb, int n) {
    __shared__ int sd[1024];
    int t = threadIdx.x;
    int v = (t < nb) ? bsum[t] : 0;
    sd[t] = v;
    __syncthreads();
    for (int off = 1; off < 1024; off <<= 1) {
        int x = (t >= off) ? sd[t - off] : 0;
        __syncthreads();
        sd[t] += x;
        __syncthreads();
    }
    if (t < nb) boff[t] = sd[t] - v;
    if (t == 1023) start[n] = sd[1023];         // grand total = E
}

// ---------------- scan stage 3: finalize start, init cursor, compute dinv ----------------
__global__ void scan3(int* __restrict__ start, int* __restrict__ cursor,
                      const int* __restrict__ boff, const float* __restrict__ deg,
                      float* __restrict__ dinv, int n) {
    int i = blockIdx.x * blockDim.x + threadIdx.x;
    if (i >= n) return;
    int s = start[i] + boff[i >> 8];            // scan1 chunk = 256
    start[i] = s;
    cursor[i] = s;
    float d = deg[i] + 1.0f;                    // + self-loop weight
    dinv[i] = d > 0.f ? rsqrtf(d) : 0.f;
}

// ---------------- edge pass 2: bin edges into CSR, pack (row, norm) ----------------
__global__ void bin_edges(const int* __restrict__ row, const int* __restrict__ col,
                          const float* __restrict__ ew, const float* __restrict__ dinv,
                          int* __restrict__ cursor, int2* __restrict__ pack, int E) {
    int e = blockIdx.x * blockDim.x + threadIdx.x;
    if (e >= E) return;
    int c = col[e], r = row[e];
    int pos = atomicAdd(&cursor[c], 1);
    pack[pos] = make_int2(r, __float_as_int(dinv[r] * ew[e] * dinv[c]));
}

// ---------------- dense: x[N,16] @ W[16,64] ----------------
__global__ void gemm_in16(const float* __restrict__ x, const float* __restrict__ W,
                          float* __restrict__ out, int n) {
    __shared__ float Ws[16 * 64];
    int t = threadIdx.x;                       // 256 threads
    for (int i = t; i < 16 * 64; i += 256) Ws[i] = W[i];
    __syncthreads();
    int node = blockIdx.x * 4 + (t >> 6);
    int j = t & 63;
    if (node >= n) return;
    const float* xr = x + (size_t)node * 16;
    float acc = 0.f;
#pragma unroll
    for (int k = 0; k < 16; ++k) acc += xr[k] * Ws[k * 64 + j];
    out[(size_t)node * 64 + j] = acc;
}

// ---------------- dense: h[N,64] @ W[64,64] ----------------
__global__ void gemm_hid(const float* __restrict__ h, const float* __restrict__ W,
                         float* __restrict__ out, int n) {
    __shared__ float Ws[64 * 64];
    int t = threadIdx.x;                       // 256 threads
    for (int i = t; i < 64 * 64; i += 256) Ws[i] = W[i];
    __syncthreads();
    int node = blockIdx.x * 4 + (t >> 6);
    int j = t & 63;
    if (node >= n) return;
    float v = h[(size_t)node * 64 + j];
    float acc = 0.f;
#pragma unroll
    for (int k = 0; k < 64; ++k)
        acc += __shfl(v, k, 64) * Ws[k * 64 + j];
    out[(size_t)node * 64 + j] = acc;
}

// ---------------- gather: one wave per node, 4 edges x float4 per iteration ----------------
// lane = 16*sub + q : sub in [0,4) = which edge of the group, q = channel quad
__global__ void gather_nodes4(const int* __restrict__ start, const int2* __restrict__ pack,
                              const float* __restrict__ hpre, const float* __restrict__ dinv,
                              const float* __restrict__ b, float* __restrict__ out,
                              int n, int do_relu) {
    int wid = (blockIdx.x * blockDim.x + threadIdx.x) >> 6;
    if (wid >= n) return;
    int lane = threadIdx.x & 63;
    int sub = lane >> 4;
    int ch4 = (lane & 15) << 2;
    int s = start[wid], e = start[wid + 1];
    float4 acc = make_float4(0.f, 0.f, 0.f, 0.f);
    int i = s;
    for (; i + 3 < e; i += 4) {
        int2 pk = pack[i + sub];
        float w = __int_as_float(pk.y);
        const float4 v = *reinterpret_cast<const float4*>(hpre + ((size_t)pk.x << 6) + ch4);
        acc.x += v.x * w; acc.y += v.y * w; acc.z += v.z * w; acc.w += v.w * w;
    }
    int rem = e - i;
    if (sub < rem) {
        int2 pk = pack[i + sub];
        float w = __int_as_float(pk.y);
        const float4 v = *reinterpret_cast<const float4*>(hpre + ((size_t)pk.x << 6) + ch4);
        acc.x += v.x * w; acc.y += v.y * w; acc.z += v.z * w; acc.w += v.w * w;
    }
    // reduce across the 4 sub-edge groups (lanes differing in bits 4,5)
#pragma unroll
    for (int m = 16; m <= 32; m <<= 1) {
        acc.x += __shfl_xor(acc.x, m, 64);
        acc.y += __shfl_xor(acc.y, m, 64);
        acc.z += __shfl_xor(acc.z, m, 64);
        acc.w += __shfl_xor(acc.w, m, 64);
    }
    if (sub == 0) {                              // lanes 0..15 write 256B contiguous
        float di = dinv[wid];
        float d2 = di * di;
        const float4 h0 = *reinterpret_cast<const float4*>(hpre + ((size_t)wid << 6) + ch4);
        const float4 bb = *reinterpret_cast<const float4*>(b + ch4);
        float4 r;
        r.x = acc.x + h0.x * d2 + bb.x;
        r.y = acc.y + h0.y * d2 + bb.y;
        r.z = acc.z + h0.z * d2 + bb.z;
        r.w = acc.w + h0.w * d2 + bb.w;
        if (do_relu) {
            r.x = fmaxf(r.x, 0.f); r.y = fmaxf(r.y, 0.f);
            r.z = fmaxf(r.z, 0.f); r.w = fmaxf(r.w, 0.f);
        }
        *reinterpret_cast<float4*>(out + ((size_t)wid << 6) + ch4) = r;
    }
}

// ---------------- head: out[n,2] = h[n,:] @ Wl + bl ----------------
__global__ void head(const float* __restrict__ h, const float* __restrict__ Wl,
                     const float* __restrict__ bl, float* __restrict__ out, int n) {
    int wave = (blockIdx.x * blockDim.x + threadIdx.x) >> 6;
    int lane = threadIdx.x & 63;
    if (wave >= n) return;
    float v = h[(size_t)wave * 64 + lane];
    float s0 = v * Wl[lane * 2 + 0];
    float s1 = v * Wl[lane * 2 + 1];
#pragma unroll
    for (int off = 32; off > 0; off >>= 1) {
        s0 += __shfl_down(s0, off, 64);
        s1 += __shfl_down(s1, off, 64);
    }
    if (lane == 0) {
        out[(size_t)wave * 2 + 0] = s0 + bl[0];
        out[(size_t)wave * 2 + 1] = s1 + bl[1];
    }
}

extern "C" void kernel_launch(void* const* d_in, const int* in_sizes, int n_in,
                              void* d_out, int out_size, void* d_ws, size_t ws_size,
                              hipStream_t stream) {
    const float* x  = (const float*)d_in[0];
    const int*   ei = (const int*)d_in[1];
    const float* ew = (const float*)d_in[2];
    const float* W1 = (const float*)d_in[3];
    const float* b1 = (const float*)d_in[4];
    const float* W2 = (const float*)d_in[5];
    const float* b2 = (const float*)d_in[6];
    const float* Wl = (const float*)d_in[7];
    const float* bl = (const float*)d_in[8];
    float* out = (float*)d_out;

    const int N = in_sizes[0] / 16;
    const int E = in_sizes[2];
    const int* row = ei;
    const int* col = ei + E;
    const int NB = (N + 255) / 256;              // scan1 blocks (<= 1024)

    // workspace layout (8B-aligned pack first)
    char* p = (char*)d_ws;
    int2*  pack   = (int2*)p;   p += (size_t)E * 8;
    float* bufA   = (float*)p;  p += (size_t)N * 64 * 4;
    float* bufB   = (float*)p;  p += (size_t)N * 64 * 4;
    float* dinv   = (float*)p;  p += (size_t)N * 4;
    float* deg    = (float*)p;  p += (size_t)N * 4;   // deg & cursor adjacent:
    int*   cursor = (int*)p;    p += (size_t)N * 4;   //   one memset covers both
    int*   startO = (int*)p;    p += (size_t)(N + 1) * 4;
    int*   bsum   = (int*)p;    p += (size_t)NB * 4;
    int*   boff   = (int*)p;    p += (size_t)NB * 4;

    // ---- build CSR by destination + dinv (shared by both layers) ----
    hipMemsetAsync(deg, 0, (size_t)2 * N * sizeof(float), stream);   // deg + cursor(cnt)
    hist_deg<<<(E + 255) / 256, 256, 0, stream>>>(col, ew, cursor, deg, E);
    scan1<<<NB, 256, 0, stream>>>(cursor, startO, bsum, N);
    scan2<<<1, 1024, 0, stream>>>(bsum, boff, startO, NB, N);
    scan3<<<NB, 256, 0, stream>>>(startO, cursor, boff, deg, dinv, N);  // cursor := start
    bin_edges<<<(E + 255) / 256, 256, 0, stream>>>(row, col, ew, dinv, cursor, pack, E);

    // ---- layer 1 ----
    gemm_in16<<<(N + 3) / 4, 256, 0, stream>>>(x, W1, bufA, N);
    gather_nodes4<<<(N + 3) / 4, 256, 0, stream>>>(startO, pack, bufA, dinv, b1, bufB, N, 1);

    // ---- layer 2 ----
    gemm_hid<<<(N + 3) / 4, 256, 0, stream>>>(bufB, W2, bufA, N);
    gather_nodes4<<<(N + 3) / 4, 256, 0, stream>>>(startO, pack, bufA, dinv, b2, bufB, N, 1);

    // ---- head ----
    head<<<(N + 3) / 4, 256, 0, stream>>>(bufB, Wl, bl, out, N);
}

// Round 4
// 268.151 us; speedup vs baseline: 7.3476x; 1.2732x over previous
//
#include <hip/hip_runtime.h>

#define FIX_SCALE 16777216.0f            // 2^24
#define SUM_BITS 44
#define SUM_MASK ((1ull << SUM_BITS) - 1)

// ---------------- edge pass 1: packed count+degree atomic, emit rank ----------------
__global__ void hist_rank(const int* __restrict__ col, const float* __restrict__ ew,
                          unsigned long long* __restrict__ packed,
                          int* __restrict__ rank, int E) {
    int e = blockIdx.x * blockDim.x + threadIdx.x;
    if (e >= E) return;
    int c = col[e];
    unsigned long long add = (1ull << SUM_BITS) |
                             (unsigned long long)(ew[e] * FIX_SCALE + 0.5f);
    unsigned long long old = atomicAdd(&packed[c], add);
    rank[e] = (int)(old >> SUM_BITS);    // this edge's arrival index at node c
}

// ---------------- scan stage 1: per-block (256) exclusive scan of counts ----------------
__global__ void scan1(const unsigned long long* __restrict__ packed, int* __restrict__ start,
                      int* __restrict__ bsum, int n) {
    __shared__ int sd[256];
    int t = threadIdx.x;
    int i = blockIdx.x * 256 + t;
    int v = (i < n) ? (int)(packed[i] >> SUM_BITS) : 0;
    sd[t] = v;
    __syncthreads();
    for (int off = 1; off < 256; off <<= 1) {   // Hillis-Steele inclusive
        int x = (t >= off) ? sd[t - off] : 0;
        __syncthreads();
        sd[t] += x;
        __syncthreads();
    }
    if (i < n) start[i] = sd[t] - v;            // local exclusive
    if (t == 255) bsum[blockIdx.x] = sd[255];   // block total
}

// ---------------- scan stage 2: single block scans block sums (nb <= 1024) ----------------
__global__ void scan2(const int* __restrict__ bsum, int* __restrict__ boff,
                      int* __restrict__ start, int nb, int n) {
    __shared__ int sd[1024];
    int t = threadIdx.x;
    int v = (t < nb) ? bsum[t] : 0;
    sd[t] = v;
    __syncthreads();
    for (int off = 1; off < 1024; off <<= 1) {
        int x = (t >= off) ? sd[t - off] : 0;
        __syncthreads();
        sd[t] += x;
        __syncthreads();
    }
    if (t < nb) boff[t] = sd[t] - v;
    if (t == 1023) start[n] = sd[1023];         // grand total = E
}

// ---------------- scan stage 3: finalize start, compute dinv ----------------
__global__ void scan3(int* __restrict__ start, const int* __restrict__ boff,
                      const unsigned long long* __restrict__ packed,
                      float* __restrict__ dinv, int n) {
    int i = blockIdx.x * blockDim.x + threadIdx.x;
    if (i >= n) return;
    start[i] += boff[i >> 8];                   // scan1 chunk = 256
    float d = (float)(double)(packed[i] & SUM_MASK) * (1.0f / FIX_SCALE) + 1.0f;
    dinv[i] = rsqrtf(d);                        // d >= 1 always (self-loop)
}

// ---------------- edge pass 2: bin edges into CSR (NO atomics) ----------------
__global__ void bin_edges(const int* __restrict__ row, const int* __restrict__ col,
                          const float* __restrict__ ew, const float* __restrict__ dinv,
                          const int* __restrict__ start, const int* __restrict__ rank,
                          int2* __restrict__ pack, int E) {
    int e = blockIdx.x * blockDim.x + threadIdx.x;
    if (e >= E) return;
    int c = col[e], r = row[e];
    int pos = start[c] + rank[e];
    pack[pos] = make_int2(r, __float_as_int(ew[e] * dinv[r]));  // dinv[c] applied in gather
}

// ---------------- dense: x[N,16] @ W[16,64] ----------------
__global__ void gemm_in16(const float* __restrict__ x, const float* __restrict__ W,
                          float* __restrict__ out, int n) {
    __shared__ float Ws[16 * 64];
    int t = threadIdx.x;                       // 256 threads
    for (int i = t; i < 16 * 64; i += 256) Ws[i] = W[i];
    __syncthreads();
    int node = blockIdx.x * 4 + (t >> 6);
    int j = t & 63;
    if (node >= n) return;
    const float* xr = x + (size_t)node * 16;
    float acc = 0.f;
#pragma unroll
    for (int k = 0; k < 16; ++k) acc += xr[k] * Ws[k * 64 + j];
    out[(size_t)node * 64 + j] = acc;
}

// ---------------- dense: h[N,64] @ W[64,64] ----------------
__global__ void gemm_hid(const float* __restrict__ h, const float* __restrict__ W,
                         float* __restrict__ out, int n) {
    __shared__ float Ws[64 * 64];
    int t = threadIdx.x;                       // 256 threads
    for (int i = t; i < 64 * 64; i += 256) Ws[i] = W[i];
    __syncthreads();
    int node = blockIdx.x * 4 + (t >> 6);
    int j = t & 63;
    if (node >= n) return;
    float v = h[(size_t)node * 64 + j];
    float acc = 0.f;
#pragma unroll
    for (int k = 0; k < 64; ++k)
        acc += __shfl(v, k, 64) * Ws[k * 64 + j];
    out[(size_t)node * 64 + j] = acc;
}

// ---------------- gather: one wave per node, 4 edges x float4 per iteration ----------------
// lane = 16*sub + q : sub in [0,4) = which edge of the group, q = channel quad
// out[c] = relu( dinv[c]*sum_e w_e*h[r_e] + h[c]*dinv[c]^2 + b )
__global__ void gather_nodes4(const int* __restrict__ start, const int2* __restrict__ pack,
                              const float* __restrict__ hpre, const float* __restrict__ dinv,
                              const float* __restrict__ b, float* __restrict__ out,
                              int n, int do_relu) {
    int wid = (blockIdx.x * blockDim.x + threadIdx.x) >> 6;
    if (wid >= n) return;
    int lane = threadIdx.x & 63;
    int sub = lane >> 4;
    int ch4 = (lane & 15) << 2;
    int s = start[wid], e = start[wid + 1];
    float4 acc = make_float4(0.f, 0.f, 0.f, 0.f);
    int i = s;
    for (; i + 3 < e; i += 4) {
        int2 pk = pack[i + sub];
        float w = __int_as_float(pk.y);
        const float4 v = *reinterpret_cast<const float4*>(hpre + ((size_t)pk.x << 6) + ch4);
        acc.x += v.x * w; acc.y += v.y * w; acc.z += v.z * w; acc.w += v.w * w;
    }
    int rem = e - i;
    if (sub < rem) {
        int2 pk = pack[i + sub];
        float w = __int_as_float(pk.y);
        const float4 v = *reinterpret_cast<const float4*>(hpre + ((size_t)pk.x << 6) + ch4);
        acc.x += v.x * w; acc.y += v.y * w; acc.z += v.z * w; acc.w += v.w * w;
    }
    // reduce across the 4 sub-edge groups (lanes differing in bits 4,5)
#pragma unroll
    for (int m = 16; m <= 32; m <<= 1) {
        acc.x += __shfl_xor(acc.x, m, 64);
        acc.y += __shfl_xor(acc.y, m, 64);
        acc.z += __shfl_xor(acc.z, m, 64);
        acc.w += __shfl_xor(acc.w, m, 64);
    }
    if (sub == 0) {                              // lanes 0..15 write 256B contiguous
        float di = dinv[wid];
        float d2 = di * di;
        const float4 h0 = *reinterpret_cast<const float4*>(hpre + ((size_t)wid << 6) + ch4);
        const float4 bb = *reinterpret_cast<const float4*>(b + ch4);
        float4 r;
        r.x = di * acc.x + h0.x * d2 + bb.x;
        r.y = di * acc.y + h0.y * d2 + bb.y;
        r.z = di * acc.z + h0.z * d2 + bb.z;
        r.w = di * acc.w + h0.w * d2 + bb.w;
        if (do_relu) {
            r.x = fmaxf(r.x, 0.f); r.y = fmaxf(r.y, 0.f);
            r.z = fmaxf(r.z, 0.f); r.w = fmaxf(r.w, 0.f);
        }
        *reinterpret_cast<float4*>(out + ((size_t)wid << 6) + ch4) = r;
    }
}

// ---------------- head: out[n,2] = h[n,:] @ Wl + bl ----------------
__global__ void head(const float* __restrict__ h, const float* __restrict__ Wl,
                     const float* __restrict__ bl, float* __restrict__ out, int n) {
    int wave = (blockIdx.x * blockDim.x + threadIdx.x) >> 6;
    int lane = threadIdx.x & 63;
    if (wave >= n) return;
    float v = h[(size_t)wave * 64 + lane];
    float s0 = v * Wl[lane * 2 + 0];
    float s1 = v * Wl[lane * 2 + 1];
#pragma unroll
    for (int off = 32; off > 0; off >>= 1) {
        s0 += __shfl_down(s0, off, 64);
        s1 += __shfl_down(s1, off, 64);
    }
    if (lane == 0) {
        out[(size_t)wave * 2 + 0] = s0 + bl[0];
        out[(size_t)wave * 2 + 1] = s1 + bl[1];
    }
}

extern "C" void kernel_launch(void* const* d_in, const int* in_sizes, int n_in,
                              void* d_out, int out_size, void* d_ws, size_t ws_size,
                              hipStream_t stream) {
    const float* x  = (const float*)d_in[0];
    const int*   ei = (const int*)d_in[1];
    const float* ew = (const float*)d_in[2];
    const float* W1 = (const float*)d_in[3];
    const float* b1 = (const float*)d_in[4];
    const float* W2 = (const float*)d_in[5];
    const float* b2 = (const float*)d_in[6];
    const float* Wl = (const float*)d_in[7];
    const float* bl = (const float*)d_in[8];
    float* out = (float*)d_out;

    const int N = in_sizes[0] / 16;
    const int E = in_sizes[2];
    const int* row = ei;
    const int* col = ei + E;
    const int NB = (N + 255) / 256;              // scan1 blocks (<= 1024)

    // workspace layout (8B-aligned first)
    char* p = (char*)d_ws;
    int2*  pack   = (int2*)p;   p += (size_t)E * 8;
    unsigned long long* packed = (unsigned long long*)p; p += (size_t)N * 8;
    float* bufA   = (float*)p;  p += (size_t)N * 64 * 4;
    float* bufB   = (float*)p;  p += (size_t)N * 64 * 4;
    float* dinv   = (float*)p;  p += (size_t)N * 4;
    int*   startO = (int*)p;    p += (size_t)(N + 1) * 4;
    int*   bsum   = (int*)p;    p += (size_t)NB * 4;
    int*   boff   = (int*)p;    p += (size_t)NB * 4;
    int*   rank   = (int*)bufB; // alias: bufB dead until layer-1 gather (after bin_edges)

    // ---- build CSR by destination + dinv (shared by both layers) ----
    hipMemsetAsync(packed, 0, (size_t)N * 8, stream);
    hist_rank<<<(E + 255) / 256, 256, 0, stream>>>(col, ew, packed, rank, E);
    scan1<<<NB, 256, 0, stream>>>(packed, startO, bsum, N);
    scan2<<<1, 1024, 0, stream>>>(bsum, boff, startO, NB, N);
    scan3<<<NB, 256, 0, stream>>>(startO, boff, packed, dinv, N);
    bin_edges<<<(E + 255) / 256, 256, 0, stream>>>(row, col, ew, dinv, startO, rank, pack, E);

    // ---- layer 1 ----
    gemm_in16<<<(N + 3) / 4, 256, 0, stream>>>(x, W1, bufA, N);
    gather_nodes4<<<(N + 3) / 4, 256, 0, stream>>>(startO, pack, bufA, dinv, b1, bufB, N, 1);

    // ---- layer 2 ----
    gemm_hid<<<(N + 3) / 4, 256, 0, stream>>>(bufB, W2, bufA, N);
    gather_nodes4<<<(N + 3) / 4, 256, 0, stream>>>(startO, pack, bufA, dinv, b2, bufB, N, 1);

    // ---- head ----
    head<<<(N + 3) / 4, 256, 0, stream>>>(bufB, Wl, bl, out, N);
}

// Round 5
// 221.005 us; speedup vs baseline: 8.9151x; 1.2133x over previous
//
#include <hip/hip_runtime.h>

#define FIX_SCALE 16777216.0f            // 2^24
#define SUM_BITS 44
#define SUM_MASK ((1ull << SUM_BITS) - 1)

// ---------------- edge pass 1: packed count+degree atomic, emit rank ----------------
__global__ void hist_rank(const int* __restrict__ col, const float* __restrict__ ew,
                          unsigned long long* __restrict__ packed,
                          int* __restrict__ rank, int E) {
    int e = blockIdx.x * blockDim.x + threadIdx.x;
    if (e >= E) return;
    int c = col[e];
    unsigned long long add = (1ull << SUM_BITS) |
                             (unsigned long long)(ew[e] * FIX_SCALE + 0.5f);
    unsigned long long old = atomicAdd(&packed[c], add);
    rank[e] = (int)(old >> SUM_BITS);    // this edge's arrival index at node c
}

// ---------------- scan stage 1: per-block (256) exclusive scan of counts ----------------
__global__ void scan1(const unsigned long long* __restrict__ packed, int* __restrict__ start,
                      int* __restrict__ bsum, int n) {
    __shared__ int sd[256];
    int t = threadIdx.x;
    int i = blockIdx.x * 256 + t;
    int v = (i < n) ? (int)(packed[i] >> SUM_BITS) : 0;
    sd[t] = v;
    __syncthreads();
    for (int off = 1; off < 256; off <<= 1) {   // Hillis-Steele inclusive
        int x = (t >= off) ? sd[t - off] : 0;
        __syncthreads();
        sd[t] += x;
        __syncthreads();
    }
    if (i < n) start[i] = sd[t] - v;            // local exclusive
    if (t == 255) bsum[blockIdx.x] = sd[255];   // block total
}

// ---------------- scan stage 2: single block scans block sums (nb <= 1024) ----------------
__global__ void scan2(const int* __restrict__ bsum, int* __restrict__ boff,
                      int* __restrict__ start, int nb, int n) {
    __shared__ int sd[1024];
    int t = threadIdx.x;
    int v = (t < nb) ? bsum[t] : 0;
    sd[t] = v;
    __syncthreads();
    for (int off = 1; off < 1024; off <<= 1) {
        int x = (t >= off) ? sd[t - off] : 0;
        __syncthreads();
        sd[t] += x;
        __syncthreads();
    }
    if (t < nb) boff[t] = sd[t] - v;
    if (t == 1023) start[n] = sd[1023];         // grand total = E
}

// ---------------- scan stage 3: finalize start, compute dinv ----------------
__global__ void scan3(int* __restrict__ start, const int* __restrict__ boff,
                      const unsigned long long* __restrict__ packed,
                      float* __restrict__ dinv, int n) {
    int i = blockIdx.x * blockDim.x + threadIdx.x;
    if (i >= n) return;
    start[i] += boff[i >> 8];                   // scan1 chunk = 256
    float d = (float)(double)(packed[i] & SUM_MASK) * (1.0f / FIX_SCALE) + 1.0f;
    dinv[i] = rsqrtf(d);                        // d >= 1 always (self-loop)
}

// ---------------- edge pass 2: bin edges into CSR (NO atomics) ----------------
__global__ void bin_edges(const int* __restrict__ row, const int* __restrict__ col,
                          const float* __restrict__ ew, const float* __restrict__ dinv,
                          const int* __restrict__ start, const int* __restrict__ rank,
                          int2* __restrict__ pack, int E) {
    int e = blockIdx.x * blockDim.x + threadIdx.x;
    if (e >= E) return;
    int c = col[e], r = row[e];
    int pos = start[c] + rank[e];
    pack[pos] = make_int2(r, __float_as_int(ew[e] * dinv[r]));  // dinv[c] applied in gather
}

// ---------------- dense: x[N,16] @ W[16,64] ----------------
__global__ void gemm_in16(const float* __restrict__ x, const float* __restrict__ W,
                          float* __restrict__ out, int n) {
    __shared__ float Ws[16 * 64];
    int t = threadIdx.x;                       // 256 threads
    for (int i = t; i < 16 * 64; i += 256) Ws[i] = W[i];
    __syncthreads();
    int node = blockIdx.x * 4 + (t >> 6);
    int j = t & 63;
    if (node >= n) return;
    const float* xr = x + (size_t)node * 16;
    float acc = 0.f;
#pragma unroll
    for (int k = 0; k < 16; ++k) acc += xr[k] * Ws[k * 64 + j];
    out[(size_t)node * 64 + j] = acc;
}

// ---------------- dense: h[N,64] @ W[64,64], register-blocked GEMV per node ----------------
// Thread t owns node = blk*256+t: h-row in 64 VGPRs; W in LDS.
// Inner: wave-uniform ds_read_b128 (broadcast, conflict-free) -> 4 FMA per LDS read.
__global__ __launch_bounds__(256) void gemm_hid(const float* __restrict__ h,
                                                const float* __restrict__ W,
                                                float* __restrict__ out, int n) {
    __shared__ float Ws[64 * 64];
    int t = threadIdx.x;                       // 256 threads
#pragma unroll
    for (int i = 0; i < 16; ++i) Ws[i * 256 + t] = W[i * 256 + t];
    __syncthreads();
    int node = blockIdx.x * 256 + t;
    if (node >= n) return;
    float hv[64];
    const float4* hr = reinterpret_cast<const float4*>(h + ((size_t)node << 6));
#pragma unroll
    for (int i = 0; i < 16; ++i)
        *reinterpret_cast<float4*>(&hv[i * 4]) = hr[i];   // L1 coalesces the 256B-stride pattern
    float4* orow = reinterpret_cast<float4*>(out + ((size_t)node << 6));
    for (int jb = 0; jb < 16; ++jb) {          // runtime loop: code size control
        float4 acc = make_float4(0.f, 0.f, 0.f, 0.f);
#pragma unroll
        for (int k = 0; k < 64; ++k) {         // k const -> hv[k] stays in registers
            float hk = hv[k];
            const float4 wv = *reinterpret_cast<const float4*>(&Ws[k * 64 + jb * 4]);
            acc.x += hk * wv.x; acc.y += hk * wv.y;
            acc.z += hk * wv.z; acc.w += hk * wv.w;
        }
        orow[jb] = acc;
    }
}

// ---------------- gather: one wave per node, 4 edges x float4 per iteration ----------------
// lane = 16*sub + q : sub in [0,4) = which edge of the group, q = channel quad
// out[c] = relu( dinv[c]*sum_e w_e*h[r_e] + h[c]*dinv[c]^2 + b )
__global__ void gather_nodes4(const int* __restrict__ start, const int2* __restrict__ pack,
                              const float* __restrict__ hpre, const float* __restrict__ dinv,
                              const float* __restrict__ b, float* __restrict__ out,
                              int n, int do_relu) {
    int wid = (blockIdx.x * blockDim.x + threadIdx.x) >> 6;
    if (wid >= n) return;
    int lane = threadIdx.x & 63;
    int sub = lane >> 4;
    int ch4 = (lane & 15) << 2;
    int s = start[wid], e = start[wid + 1];
    float4 acc = make_float4(0.f, 0.f, 0.f, 0.f);
    int i = s;
    for (; i + 3 < e; i += 4) {
        int2 pk = pack[i + sub];
        float w = __int_as_float(pk.y);
        const float4 v = *reinterpret_cast<const float4*>(hpre + ((size_t)pk.x << 6) + ch4);
        acc.x += v.x * w; acc.y += v.y * w; acc.z += v.z * w; acc.w += v.w * w;
    }
    int rem = e - i;
    if (sub < rem) {
        int2 pk = pack[i + sub];
        float w = __int_as_float(pk.y);
        const float4 v = *reinterpret_cast<const float4*>(hpre + ((size_t)pk.x << 6) + ch4);
        acc.x += v.x * w; acc.y += v.y * w; acc.z += v.z * w; acc.w += v.w * w;
    }
    // reduce across the 4 sub-edge groups (lanes differing in bits 4,5)
#pragma unroll
    for (int m = 16; m <= 32; m <<= 1) {
        acc.x += __shfl_xor(acc.x, m, 64);
        acc.y += __shfl_xor(acc.y, m, 64);
        acc.z += __shfl_xor(acc.z, m, 64);
        acc.w += __shfl_xor(acc.w, m, 64);
    }
    if (sub == 0) {                              // lanes 0..15 write 256B contiguous
        float di = dinv[wid];
        float d2 = di * di;
        const float4 h0 = *reinterpret_cast<const float4*>(hpre + ((size_t)wid << 6) + ch4);
        const float4 bb = *reinterpret_cast<const float4*>(b + ch4);
        float4 r;
        r.x = di * acc.x + h0.x * d2 + bb.x;
        r.y = di * acc.y + h0.y * d2 + bb.y;
        r.z = di * acc.z + h0.z * d2 + bb.z;
        r.w = di * acc.w + h0.w * d2 + bb.w;
        if (do_relu) {
            r.x = fmaxf(r.x, 0.f); r.y = fmaxf(r.y, 0.f);
            r.z = fmaxf(r.z, 0.f); r.w = fmaxf(r.w, 0.f);
        }
        *reinterpret_cast<float4*>(out + ((size_t)wid << 6) + ch4) = r;
    }
}

// ---------------- head: out[n,2] = h[n,:] @ Wl + bl ----------------
__global__ void head(const float* __restrict__ h, const float* __restrict__ Wl,
                     const float* __restrict__ bl, float* __restrict__ out, int n) {
    int wave = (blockIdx.x * blockDim.x + threadIdx.x) >> 6;
    int lane = threadIdx.x & 63;
    if (wave >= n) return;
    float v = h[(size_t)wave * 64 + lane];
    float s0 = v * Wl[lane * 2 + 0];
    float s1 = v * Wl[lane * 2 + 1];
#pragma unroll
    for (int off = 32; off > 0; off >>= 1) {
        s0 += __shfl_down(s0, off, 64);
        s1 += __shfl_down(s1, off, 64);
    }
    if (lane == 0) {
        out[(size_t)wave * 2 + 0] = s0 + bl[0];
        out[(size_t)wave * 2 + 1] = s1 + bl[1];
    }
}

extern "C" void kernel_launch(void* const* d_in, const int* in_sizes, int n_in,
                              void* d_out, int out_size, void* d_ws, size_t ws_size,
                              hipStream_t stream) {
    const float* x  = (const float*)d_in[0];
    const int*   ei = (const int*)d_in[1];
    const float* ew = (const float*)d_in[2];
    const float* W1 = (const float*)d_in[3];
    const float* b1 = (const float*)d_in[4];
    const float* W2 = (const float*)d_in[5];
    const float* b2 = (const float*)d_in[6];
    const float* Wl = (const float*)d_in[7];
    const float* bl = (const float*)d_in[8];
    float* out = (float*)d_out;

    const int N = in_sizes[0] / 16;
    const int E = in_sizes[2];
    const int* row = ei;
    const int* col = ei + E;
    const int NB = (N + 255) / 256;              // scan1 blocks (<= 1024)

    // workspace layout (8B-aligned first)
    char* p = (char*)d_ws;
    int2*  pack   = (int2*)p;   p += (size_t)E * 8;
    unsigned long long* packed = (unsigned long long*)p; p += (size_t)N * 8;
    float* bufA   = (float*)p;  p += (size_t)N * 64 * 4;
    float* bufB   = (float*)p;  p += (size_t)N * 64 * 4;
    float* dinv   = (float*)p;  p += (size_t)N * 4;
    int*   startO = (int*)p;    p += (size_t)(N + 1) * 4;
    int*   bsum   = (int*)p;    p += (size_t)NB * 4;
    int*   boff   = (int*)p;    p += (size_t)NB * 4;
    int*   rank   = (int*)bufB; // alias: bufB dead until layer-1 gather (after bin_edges)

    // ---- build CSR by destination + dinv (shared by both layers) ----
    hipMemsetAsync(packed, 0, (size_t)N * 8, stream);
    hist_rank<<<(E + 255) / 256, 256, 0, stream>>>(col, ew, packed, rank, E);
    scan1<<<NB, 256, 0, stream>>>(packed, startO, bsum, N);
    scan2<<<1, 1024, 0, stream>>>(bsum, boff, startO, NB, N);
    scan3<<<NB, 256, 0, stream>>>(startO, boff, packed, dinv, N);
    bin_edges<<<(E + 255) / 256, 256, 0, stream>>>(row, col, ew, dinv, startO, rank, pack, E);

    // ---- layer 1 ----
    gemm_in16<<<(N + 3) / 4, 256, 0, stream>>>(x, W1, bufA, N);
    gather_nodes4<<<(N + 3) / 4, 256, 0, stream>>>(startO, pack, bufA, dinv, b1, bufB, N, 1);

    // ---- layer 2 ----
    gemm_hid<<<(N + 255) / 256, 256, 0, stream>>>(bufB, W2, bufA, N);
    gather_nodes4<<<(N + 3) / 4, 256, 0, stream>>>(startO, pack, bufA, dinv, b2, bufB, N, 1);

    // ---- head ----
    head<<<(N + 3) / 4, 256, 0, stream>>>(bufB, Wl, bl, out, N);
}

// Round 6
// 188.223 us; speedup vs baseline: 10.4678x; 1.1742x over previous
//
#include <hip/hip_runtime.h>

#define FIX_SCALE 16777216.0f            // 2^24
#define SUM_BITS 44
#define SUM_MASK ((1ull << SUM_BITS) - 1)

// ---------------- edge pass 1: packed count+degree atomic, emit rank ----------------
__global__ void hist_rank(const int* __restrict__ col, const float* __restrict__ ew,
                          unsigned long long* __restrict__ packed,
                          int* __restrict__ rank, int E) {
    int e = blockIdx.x * blockDim.x + threadIdx.x;
    if (e >= E) return;
    int c = col[e];
    unsigned long long add = (1ull << SUM_BITS) |
                             (unsigned long long)(ew[e] * FIX_SCALE + 0.5f);
    unsigned long long old = atomicAdd(&packed[c], add);
    rank[e] = (int)(old >> SUM_BITS);    // this edge's arrival index at node c
}

// ---------------- scan stage 1: per-block (256) exclusive scan of counts ----------------
__global__ void scan1(const unsigned long long* __restrict__ packed, int* __restrict__ start,
                      int* __restrict__ bsum, int n) {
    __shared__ int sd[256];
    int t = threadIdx.x;
    int i = blockIdx.x * 256 + t;
    int v = (i < n) ? (int)(packed[i] >> SUM_BITS) : 0;
    sd[t] = v;
    __syncthreads();
    for (int off = 1; off < 256; off <<= 1) {   // Hillis-Steele inclusive
        int x = (t >= off) ? sd[t - off] : 0;
        __syncthreads();
        sd[t] += x;
        __syncthreads();
    }
    if (i < n) start[i] = sd[t] - v;            // local exclusive
    if (t == 255) bsum[blockIdx.x] = sd[255];   // block total
}

// ---------------- scan stage 2: single block scans block sums (nb <= 1024) ----------------
__global__ void scan2(const int* __restrict__ bsum, int* __restrict__ boff,
                      int* __restrict__ start, int nb, int n) {
    __shared__ int sd[1024];
    int t = threadIdx.x;
    int v = (t < nb) ? bsum[t] : 0;
    sd[t] = v;
    __syncthreads();
    for (int off = 1; off < 1024; off <<= 1) {
        int x = (t >= off) ? sd[t - off] : 0;
        __syncthreads();
        sd[t] += x;
        __syncthreads();
    }
    if (t < nb) boff[t] = sd[t] - v;
    if (t == 1023) start[n] = sd[1023];         // grand total = E
}

// ---------------- scan stage 3: finalize start, compute dinv ----------------
__global__ void scan3(int* __restrict__ start, const int* __restrict__ boff,
                      const unsigned long long* __restrict__ packed,
                      float* __restrict__ dinv, int n) {
    int i = blockIdx.x * blockDim.x + threadIdx.x;
    if (i >= n) return;
    start[i] += boff[i >> 8];                   // scan1 chunk = 256
    float d = (float)(double)(packed[i] & SUM_MASK) * (1.0f / FIX_SCALE) + 1.0f;
    dinv[i] = rsqrtf(d);                        // d >= 1 always (self-loop)
}

// ---------------- fused: gemm_in16 (blocks [0,gb)) + bin_edges (blocks [gb,..)) ----------------
// gemm part: g1[node] = dinv[node] * (x[node,:16] @ W1)   (thread = node, W1 in LDS)
// bin part:  pack[start[c]+rank[e]] = (row, ew)           (no atomics, no dinv)
__global__ __launch_bounds__(256) void gemm16_bin(
        const float* __restrict__ x, const float* __restrict__ W1,
        const float* __restrict__ dinv, float* __restrict__ g1,
        const int* __restrict__ row, const int* __restrict__ col,
        const float* __restrict__ ew, const int* __restrict__ start,
        const int* __restrict__ rank, int2* __restrict__ pack,
        int n, int E, int gemmBlocks) {
    __shared__ float Ws[16 * 64];
    int t = threadIdx.x;
    if ((int)blockIdx.x < gemmBlocks) {
        reinterpret_cast<float4*>(Ws)[t] = reinterpret_cast<const float4*>(W1)[t];
        __syncthreads();
        int node = blockIdx.x * 256 + t;
        if (node >= n) return;
        float xv[16];
        const float4* xr = reinterpret_cast<const float4*>(x + (size_t)node * 16);
#pragma unroll
        for (int i = 0; i < 4; ++i)
            *reinterpret_cast<float4*>(&xv[i * 4]) = xr[i];   // coalesced
        float di = dinv[node];
        float4* orow = reinterpret_cast<float4*>(g1 + ((size_t)node << 6));
        for (int jb = 0; jb < 16; ++jb) {
            float4 acc = make_float4(0.f, 0.f, 0.f, 0.f);
#pragma unroll
            for (int k = 0; k < 16; ++k) {
                float hk = xv[k];
                const float4 wv = *reinterpret_cast<const float4*>(&Ws[k * 64 + jb * 4]);
                acc.x += hk * wv.x; acc.y += hk * wv.y;
                acc.z += hk * wv.z; acc.w += hk * wv.w;
            }
            acc.x *= di; acc.y *= di; acc.z *= di; acc.w *= di;
            orow[jb] = acc;
        }
    } else {
        int e = ((int)blockIdx.x - gemmBlocks) * 256 + t;
        if (e >= E) return;
        int c = col[e];
        int pos = start[c] + rank[e];
        pack[pos] = make_int2(row[e], __float_as_int(ew[e]));
    }
}

// ---------------- dense: h[N,64] @ W[64,64] -> g2 = dinv*(h@W2) ----------------
__global__ __launch_bounds__(256) void gemm_hid(const float* __restrict__ h,
                                                const float* __restrict__ W,
                                                const float* __restrict__ dinv,
                                                float* __restrict__ out, int n) {
    __shared__ float Ws[64 * 64];
    int t = threadIdx.x;                       // 256 threads
#pragma unroll
    for (int i = 0; i < 16; ++i) Ws[i * 256 + t] = W[i * 256 + t];
    __syncthreads();
    int node = blockIdx.x * 256 + t;
    if (node >= n) return;
    float hv[64];
    const float4* hr = reinterpret_cast<const float4*>(h + ((size_t)node << 6));
#pragma unroll
    for (int i = 0; i < 16; ++i)
        *reinterpret_cast<float4*>(&hv[i * 4]) = hr[i];
    float di = dinv[node];
    float4* orow = reinterpret_cast<float4*>(out + ((size_t)node << 6));
    for (int jb = 0; jb < 16; ++jb) {
        float4 acc = make_float4(0.f, 0.f, 0.f, 0.f);
#pragma unroll
        for (int k = 0; k < 64; ++k) {
            float hk = hv[k];
            const float4 wv = *reinterpret_cast<const float4*>(&Ws[k * 64 + jb * 4]);
            acc.x += hk * wv.x; acc.y += hk * wv.y;
            acc.z += hk * wv.z; acc.w += hk * wv.w;
        }
        acc.x *= di; acc.y *= di; acc.z *= di; acc.w *= di;
        orow[jb] = acc;
    }
}

// ---------------- shared gather body: 4 subs x float4, 8 edges in flight ----------------
__device__ __forceinline__ float4 gather_acc(const int* __restrict__ start,
                                             const int2* __restrict__ pack,
                                             const float* __restrict__ g,
                                             int wid, int sub, int ch4) {
    int s = start[wid], e = start[wid + 1];
    float4 acc = make_float4(0.f, 0.f, 0.f, 0.f);
    int i = s;
    for (; i + 7 < e; i += 8) {                 // 8 edges in flight per wave
        int2 pa = pack[i + sub];
        int2 pb = pack[i + 4 + sub];
        float wa = __int_as_float(pa.y), wb = __int_as_float(pb.y);
        const float4 va = *reinterpret_cast<const float4*>(g + ((size_t)pa.x << 6) + ch4);
        const float4 vb = *reinterpret_cast<const float4*>(g + ((size_t)pb.x << 6) + ch4);
        acc.x += va.x * wa; acc.y += va.y * wa; acc.z += va.z * wa; acc.w += va.w * wa;
        acc.x += vb.x * wb; acc.y += vb.y * wb; acc.z += vb.z * wb; acc.w += vb.w * wb;
    }
    if (i + 3 < e) {                            // >=4 remain
        int2 pa = pack[i + sub];
        float wa = __int_as_float(pa.y);
        const float4 va = *reinterpret_cast<const float4*>(g + ((size_t)pa.x << 6) + ch4);
        acc.x += va.x * wa; acc.y += va.y * wa; acc.z += va.z * wa; acc.w += va.w * wa;
        i += 4;
    }
    int rem = e - i;                            // 0..3
    if (sub < rem) {
        int2 pa = pack[i + sub];
        float wa = __int_as_float(pa.y);
        const float4 va = *reinterpret_cast<const float4*>(g + ((size_t)pa.x << 6) + ch4);
        acc.x += va.x * wa; acc.y += va.y * wa; acc.z += va.z * wa; acc.w += va.w * wa;
    }
#pragma unroll
    for (int m = 16; m <= 32; m <<= 1) {        // reduce across 4 sub groups
        acc.x += __shfl_xor(acc.x, m, 64);
        acc.y += __shfl_xor(acc.y, m, 64);
        acc.z += __shfl_xor(acc.z, m, 64);
        acc.w += __shfl_xor(acc.w, m, 64);
    }
    return acc;
}

// ---------------- gather (mid layer): h_out = relu(di*(acc + g[c]) + b) ----------------
__global__ __launch_bounds__(256) void gather_mid(const int* __restrict__ start,
                                                  const int2* __restrict__ pack,
                                                  const float* __restrict__ g,
                                                  const float* __restrict__ dinv,
                                                  const float* __restrict__ b,
                                                  float* __restrict__ out, int n) {
    int wid = (blockIdx.x * blockDim.x + threadIdx.x) >> 6;
    if (wid >= n) return;
    int lane = threadIdx.x & 63;
    int sub = lane >> 4;
    int ch4 = (lane & 15) << 2;
    float4 acc = gather_acc(start, pack, g, wid, sub, ch4);
    if (sub == 0) {                              // lanes 0..15 write 256B contiguous
        float di = dinv[wid];
        const float4 g0 = *reinterpret_cast<const float4*>(g + ((size_t)wid << 6) + ch4);
        const float4 bb = *reinterpret_cast<const float4*>(b + ch4);
        float4 r;
        r.x = fmaxf(di * (acc.x + g0.x) + bb.x, 0.f);
        r.y = fmaxf(di * (acc.y + g0.y) + bb.y, 0.f);
        r.z = fmaxf(di * (acc.z + g0.z) + bb.z, 0.f);
        r.w = fmaxf(di * (acc.w + g0.w) + bb.w, 0.f);
        *reinterpret_cast<float4*>(out + ((size_t)wid << 6) + ch4) = r;
    }
}

// ---------------- gather (final layer) + head fused: out[c,0:2] ----------------
__global__ __launch_bounds__(256) void gather_head(const int* __restrict__ start,
                                                   const int2* __restrict__ pack,
                                                   const float* __restrict__ g,
                                                   const float* __restrict__ dinv,
                                                   const float* __restrict__ b,
                                                   const float* __restrict__ Wl,
                                                   const float* __restrict__ bl,
                                                   float* __restrict__ out, int n) {
    int wid = (blockIdx.x * blockDim.x + threadIdx.x) >> 6;
    if (wid >= n) return;
    int lane = threadIdx.x & 63;
    int sub = lane >> 4;
    int ch4 = (lane & 15) << 2;
    float4 acc = gather_acc(start, pack, g, wid, sub, ch4);
    if (sub == 0) {
        float di = dinv[wid];
        const float4 g0 = *reinterpret_cast<const float4*>(g + ((size_t)wid << 6) + ch4);
        const float4 bb = *reinterpret_cast<const float4*>(b + ch4);
        float4 h;
        h.x = fmaxf(di * (acc.x + g0.x) + bb.x, 0.f);
        h.y = fmaxf(di * (acc.y + g0.y) + bb.y, 0.f);
        h.z = fmaxf(di * (acc.z + g0.z) + bb.z, 0.f);
        h.w = fmaxf(di * (acc.w + g0.w) + bb.w, 0.f);
        // head: s0/s1 partials over this lane's 4 channels
        float s0 = h.x * Wl[(ch4 + 0) * 2] + h.y * Wl[(ch4 + 1) * 2] +
                   h.z * Wl[(ch4 + 2) * 2] + h.w * Wl[(ch4 + 3) * 2];
        float s1 = h.x * Wl[(ch4 + 0) * 2 + 1] + h.y * Wl[(ch4 + 1) * 2 + 1] +
                   h.z * Wl[(ch4 + 2) * 2 + 1] + h.w * Wl[(ch4 + 3) * 2 + 1];
#pragma unroll
        for (int m = 1; m <= 8; m <<= 1) {       // reduce across lanes 0..15
            s0 += __shfl_xor(s0, m, 64);
            s1 += __shfl_xor(s1, m, 64);
        }
        if (lane == 0) {
            out[(size_t)wid * 2 + 0] = s0 + bl[0];
            out[(size_t)wid * 2 + 1] = s1 + bl[1];
        }
    }
}

extern "C" void kernel_launch(void* const* d_in, const int* in_sizes, int n_in,
                              void* d_out, int out_size, void* d_ws, size_t ws_size,
                              hipStream_t stream) {
    const float* x  = (const float*)d_in[0];
    const int*   ei = (const int*)d_in[1];
    const float* ew = (const float*)d_in[2];
    const float* W1 = (const float*)d_in[3];
    const float* b1 = (const float*)d_in[4];
    const float* W2 = (const float*)d_in[5];
    const float* b2 = (const float*)d_in[6];
    const float* Wl = (const float*)d_in[7];
    const float* bl = (const float*)d_in[8];
    float* out = (float*)d_out;

    const int N = in_sizes[0] / 16;
    const int E = in_sizes[2];
    const int* row = ei;
    const int* col = ei + E;
    const int NB  = (N + 255) / 256;             // scan1 / gemm blocks
    const int NBE = (E + 255) / 256;             // edge-pass blocks

    // workspace layout (8B-aligned first)
    char* p = (char*)d_ws;
    int2*  pack   = (int2*)p;   p += (size_t)E * 8;
    unsigned long long* packed = (unsigned long long*)p; p += (size_t)N * 8;
    float* bufA   = (float*)p;  p += (size_t)N * 64 * 4;   // g1 / g2
    float* bufB   = (float*)p;  p += (size_t)N * 64 * 4;   // h (mid) ; rank alias
    float* dinv   = (float*)p;  p += (size_t)N * 4;
    int*   startO = (int*)p;    p += (size_t)(N + 1) * 4;
    int*   bsum   = (int*)p;    p += (size_t)NB * 4;
    int*   boff   = (int*)p;    p += (size_t)NB * 4;
    int*   rank   = (int*)bufB; // alias: bufB dead until gather_mid writes it

    // ---- CSR build + dinv (shared by both layers) ----
    hipMemsetAsync(packed, 0, (size_t)N * 8, stream);
    hist_rank<<<NBE, 256, 0, stream>>>(col, ew, packed, rank, E);
    scan1<<<NB, 256, 0, stream>>>(packed, startO, bsum, N);
    scan2<<<1, 1024, 0, stream>>>(bsum, boff, startO, NB, N);
    scan3<<<NB, 256, 0, stream>>>(startO, boff, packed, dinv, N);

    // ---- fused: layer-1 GEMM (g1 = dinv*(x@W1)) + edge binning ----
    gemm16_bin<<<NB + NBE, 256, 0, stream>>>(x, W1, dinv, bufA,
                                             row, col, ew, startO, rank, pack,
                                             N, E, NB);

    // ---- layer 1 aggregate + relu -> h ----
    gather_mid<<<(N + 3) / 4, 256, 0, stream>>>(startO, pack, bufA, dinv, b1, bufB, N);

    // ---- layer 2 GEMM: g2 = dinv*(h@W2) ----
    gemm_hid<<<NB, 256, 0, stream>>>(bufB, W2, dinv, bufA, N);

    // ---- layer 2 aggregate + relu + head -> out ----
    gather_head<<<(N + 3) / 4, 256, 0, stream>>>(startO, pack, bufA, dinv, b2, Wl, bl, out, N);
}